// Round 21
// baseline (77.342 us; speedup 1.0000x reference)
//
#include <hip/hip_runtime.h>
#include <hip/hip_bf16.h>

typedef __attribute__((ext_vector_type(8))) short short8;   // 8 bf16 = MFMA A/B frag
typedef __attribute__((ext_vector_type(4))) short short4v;  // 4 bf16
typedef __attribute__((ext_vector_type(4))) float f32x4;    // MFMA C/D
typedef __attribute__((ext_vector_type(4))) unsigned int uint32x4;

#define MFMA16(A,B,C) __builtin_amdgcn_mfma_f32_16x16x32_bf16((A),(B),(C),0,0,0)

static __device__ __forceinline__ unsigned short f2bf(float f) {
  return __builtin_bit_cast(unsigned short, __float2bfloat16(f));  // single v_cvt, RTNE
}

// ---------------- prep: tables in MFMA-fragment order (identical to R11) ----------------
__global__ void prep_kernel(const float* __restrict__ qg,
                            const float* __restrict__ wqkv,
                            const float* __restrict__ wproj,
                            const float* __restrict__ btab,
                            unsigned short* __restrict__ wq_c,
                            unsigned short* __restrict__ wp_c,
                            unsigned short* __restrict__ q_bf,
                            float* __restrict__ bias_c)
{
  const int t = blockIdx.x * 256 + threadIdx.x;
  if (t < 32*6*64*32) {
    const int d = t & 31, n = (t >> 5) & 63;
    const int bh = t >> 11;
    const int h = bh % 6, b = bh / 6;
    float v = 0.f;
    if (n < 49) v = qg[((b * 6 + h) * 49 + n) * 32 + d] * 0.17677669529663687f;
    q_bf[t] = f2bf(v);
  }
  if (t < 8*3*6*64*8) {
    const int e = t & 7, l = (t >> 3) & 63;
    const int kb = (t >> 9) % 6, g = (t >> 9) / 6;
    const int ct = g % 3, wv = g / 3;
    const int j = wv * 48 + ct * 16 + (l & 15);
    const int c = kb * 32 + (l >> 4) * 8 + e;
    wq_c[t] = f2bf(wqkv[j * 192 + c]);
  }
  if (t < 2*6*6*64*8) {
    const int e = t & 7, l = (t >> 3) & 63;
    const int kb = (t >> 9) % 6, g = (t >> 9) / 6;
    const int ct = g % 6, cc = g / 6;
    const int cp = cc * 96 + ct * 16 + (l & 15);
    const int c = kb * 32 + (l >> 4) * 8 + e;
    wp_c[t] = f2bf(wproj[cp * 192 + c]);
  }
  if (t < 6*4*64*16) {
    const int i4 = t & 15;
    const int mt = i4 >> 2, r = i4 & 3;
    const int l = (t >> 4) & 63;
    const int nt = (t >> 10) & 3;
    const int h = t >> 12;
    // PERMUTED m so that P values land in PV A-frag order in-lane (no shuffle)
    const int m = (l >> 4) * 8 + (mt & 1) * 4 + r + (mt >> 1) * 32;
    const int n = nt * 16 + (l & 15);
    float v;
    if (m >= 49) v = -1e30f;            // mask padded keys (exp -> 0)
    else if (n >= 49) v = 0.f;          // padded query rows: any finite value
    else {
      const int ci = n / 7, cj = n % 7, mi = m / 7, mj = m % 7;
      const int idx = (ci - mi + 6) * 13 + (cj - mj + 6);
      v = btab[idx * 6 + h];
    }
    bias_c[t] = v;
  }
}

// ---------------- fused window attention (R20 + register-lean line-owner stage 4) ----------------
// LDS: x_lds[64][200] @0 | k_lds[6][64][36] @12800 | vT_lds[6][32][68] @26624
//   o_lds[64][200] @0 (aliases dead x). total 79360 B -> 2 blocks/CU. 3 barriers.
// Stage 4 v5: 12 items = 6 col-PAIRS (full 128B lines, one owner wave -> no
// half-dirty evictions, R20's win) x 2 row-halves (acc2[2][2]=16 VGPR, not 32 ->
// no spill, kills R20's residual ~20MiB WRITE junk). All 8 waves participate.
// B loaded once per item (2x wp_c L2 traffic vs R20; still 2x better than R16).
// __launch_bounds__(512,4): 64-VGPR envelope; verify no-spill via WRITE_SIZE ~80MB.
__global__ __launch_bounds__(512, 4)
void fused_win_attn(const float* __restrict__ x,
                    const float* __restrict__ b_qkv,
                    const float* __restrict__ b_proj,
                    const unsigned short* __restrict__ wq_c,
                    const unsigned short* __restrict__ wp_c,
                    const unsigned short* __restrict__ q_bf,
                    const float* __restrict__ bias_c,
                    float* __restrict__ out)
{
  extern __shared__ unsigned short lds[];
  unsigned short* x_lds  = lds;
  unsigned short* k_lds  = lds + 12800;
  unsigned short* vT_lds = lds + 26624;
  unsigned short* o_lds  = lds;           // aliases dead x region during stage 3+

  const f32x4 ZERO4 = {0.f, 0.f, 0.f, 0.f};
  const int tid = threadIdx.x;
  const int wv = tid >> 6;
  const int l  = tid & 63;
  const int lr = l & 15;
  const int lq = l >> 4;
  const int w  = blockIdx.x;

  // ---- stage 1: x -> LDS bf16, zero-pad rows 49..63
  {
    const float* xw = x + (size_t)w * (49 * 192);
    for (int i = tid; i < 2352; i += 512) {
      const float4 v = *reinterpret_cast<const float4*>(xw + i * 4);
      const int e = i * 4;
      const int row = e / 192, col = e % 192;
      short4v pk;
      pk[0] = (short)f2bf(v.x); pk[1] = (short)f2bf(v.y);
      pk[2] = (short)f2bf(v.z); pk[3] = (short)f2bf(v.w);
      *reinterpret_cast<short4v*>(&x_lds[row * 200 + col]) = pk;
    }
    for (int i = tid; i < 720; i += 512) {
      const int e = i * 4;
      const int row = 49 + e / 192, col = e % 192;
      short4v z = {0, 0, 0, 0};
      *reinterpret_cast<short4v*>(&x_lds[row * 200 + col]) = z;
    }
  }
  __syncthreads();

  // ---- stage 2: kv = x @ w_qkv^T + b_qkv  -> k_lds, vT_lds (bf16)
  {
    short8 afr[4][6];
#pragma unroll
    for (int mt = 0; mt < 4; ++mt)
#pragma unroll
      for (int kb = 0; kb < 6; ++kb)
        afr[mt][kb] = *reinterpret_cast<const short8*>(
            &x_lds[(mt * 16 + lr) * 200 + kb * 32 + lq * 8]);

    for (int ct = 0; ct < 3; ++ct) {
      const int j = wv * 48 + ct * 16 + lr;   // 0..383
      short8 bfr[6];
#pragma unroll
      for (int kb = 0; kb < 6; ++kb)
        bfr[kb] = *reinterpret_cast<const short8*>(
            &wq_c[((((wv * 3) + ct) * 6 + kb) * 64 + l) * 8]);
      const float bq = b_qkv[j];
      f32x4 acc[4];
#pragma unroll
      for (int mt = 0; mt < 4; ++mt) acc[mt] = ZERO4;
#pragma unroll
      for (int kb = 0; kb < 6; ++kb)
#pragma unroll
        for (int mt = 0; mt < 4; ++mt)
          acc[mt] = MFMA16(afr[mt][kb], bfr[kb], acc[mt]);

      if (j < 192) {                  // K: k_lds[h][n][36-pad]
        const int h = j >> 5, d = j & 31;
#pragma unroll
        for (int mt = 0; mt < 4; ++mt) {
          const int n0 = mt * 16 + lq * 4;
#pragma unroll
          for (int r = 0; r < 4; ++r)
            k_lds[h * 2304 + (n0 + r) * 36 + d] = f2bf(acc[mt][r] + bq);
        }
      } else {                        // V: vT_lds[h][d][68-pad]
        const int jj = j - 192, h = jj >> 5, d = jj & 31;
#pragma unroll
        for (int mt = 0; mt < 4; ++mt) {
          const int n0 = mt * 16 + lq * 4;
          short4v pk;
#pragma unroll
          for (int r = 0; r < 4; ++r) pk[r] = (short)f2bf(acc[mt][r] + bq);
          *reinterpret_cast<short4v*>(&vT_lds[h * 2176 + d * 68 + n0]) = pk;
        }
      }
    }
  }
  __syncthreads();   // x dead; o_lds (@0) writable in stage 3

  // ---- stage 3: attention, permuted swapped QK^T; normalized O written directly
  const int nt = wv & 3;
  const int img = w >> 6;
  const int rowbase = (lr >> 2) * 8 + (lr & 3);   // permuted K-row base per lane
#pragma unroll
  for (int rd = 0; rd < 3; ++rd) {
    const int h = (wv >> 2) + 2 * rd;
    const short8 aq = *reinterpret_cast<const short8*>(
        &q_bf[((img * 6 + h) * 64 + nt * 16 + lr) * 32 + lq * 8]);
    f32x4 s[4];
#pragma unroll
    for (int mt = 0; mt < 4; ++mt) {
      const int row = rowbase + (mt & 1) * 4 + (mt >> 1) * 32;   // f(mt, lr)
      const unsigned short* kp = &k_lds[h * 2304 + row * 36 + lq * 8];
      const short4v k0 = *reinterpret_cast<const short4v*>(kp);
      const short4v k1 = *reinterpret_cast<const short4v*>(kp + 4);
      short8 bk;
      bk[0]=k0[0]; bk[1]=k0[1]; bk[2]=k0[2]; bk[3]=k0[3];
      bk[4]=k1[0]; bk[5]=k1[1]; bk[6]=k1[2]; bk[7]=k1[3];
      s[mt] = MFMA16(bk, aq, ZERO4);          // D = S^T (permuted m order)
    }
    // bias + exp; pack P (unnormalized) into PV A-frag order IN-LANE
    const float* bc = bias_c + ((h * 4 + nt) * 64 + l) * 16;
    float lsum = 0.f;
    unsigned int pa_u[4][2];
#pragma unroll
    for (int mt = 0; mt < 4; ++mt) {
      const float4 b4 = *reinterpret_cast<const float4*>(bc + mt * 4);
      const float p0 = __expf(s[mt][0] + b4.x);
      const float p1 = __expf(s[mt][1] + b4.y);
      const float p2 = __expf(s[mt][2] + b4.z);
      const float p3 = __expf(s[mt][3] + b4.w);
      lsum += (p0 + p1) + (p2 + p3);
      pa_u[mt][0] = (unsigned int)f2bf(p0) | ((unsigned int)f2bf(p1) << 16);
      pa_u[mt][1] = (unsigned int)f2bf(p2) | ((unsigned int)f2bf(p3) << 16);
    }
    lsum += __shfl_xor(lsum, 16, 64);
    lsum += __shfl_xor(lsum, 32, 64);
    const float rs = 1.0f / lsum;
    float rinv[4];
#pragma unroll
    for (int r = 0; r < 4; ++r)
      rinv[r] = __shfl(rs, lq * 4 + r, 16);
    // PV: pa[kb] = {p[2kb][0..3], p[2kb+1][0..3]} — no LDS, no shuffle
    f32x4 o0 = ZERO4, o1 = ZERO4;
#pragma unroll
    for (int kb = 0; kb < 2; ++kb) {
      uint32x4 uu;
      uu[0] = pa_u[2*kb][0]; uu[1] = pa_u[2*kb][1];
      uu[2] = pa_u[2*kb+1][0]; uu[3] = pa_u[2*kb+1][1];
      const short8 pa = __builtin_bit_cast(short8, uu);
      const unsigned short* vp0 = &vT_lds[h * 2176 + lr * 68 + kb * 32 + lq * 8];
      const unsigned short* vp1 = &vT_lds[h * 2176 + (16 + lr) * 68 + kb * 32 + lq * 8];
      const short4v a0 = *reinterpret_cast<const short4v*>(vp0);
      const short4v a1 = *reinterpret_cast<const short4v*>(vp0 + 4);
      short8 bv0; bv0[0]=a0[0];bv0[1]=a0[1];bv0[2]=a0[2];bv0[3]=a0[3];
                  bv0[4]=a1[0];bv0[5]=a1[1];bv0[6]=a1[2];bv0[7]=a1[3];
      o0 = MFMA16(pa, bv0, o0);
      const short4v c0 = *reinterpret_cast<const short4v*>(vp1);
      const short4v c1 = *reinterpret_cast<const short4v*>(vp1 + 4);
      short8 bv1; bv1[0]=c0[0];bv1[1]=c0[1];bv1[2]=c0[2];bv1[3]=c0[3];
                  bv1[4]=c1[0];bv1[5]=c1[1];bv1[6]=c1[2];bv1[7]=c1[3];
      o1 = MFMA16(pa, bv1, o1);
    }
    // normalized O -> o_lds (x region, dead) immediately
#pragma unroll
    for (int r = 0; r < 4; ++r) {
      const int n = nt * 16 + lq * 4 + r;
      o_lds[n * 200 + h * 32 + lr]      = f2bf(o0[r] * rinv[r]);
      o_lds[n * 200 + h * 32 + 16 + lr] = f2bf(o1[r] * rinv[r]);
    }
  }
  __syncthreads();   // O complete

  // ---- stage 4 v5: 12 items = 6 col-pairs x 2 row-halves over 8 waves
  {
    float* op = out + (size_t)w * 9408;
#pragma unroll 1
    for (int item = wv; item < 12; item += 8) {
      const int p  = item >> 1;            // col-pair 0..5 (cols p*32..p*32+31)
      const int hf = item & 1;             // row-half (mt 2hf, 2hf+1)
      const int cb0 = p * 2, cb1 = cb0 + 1;
      const int cp0 = cb0 * 16 + lr, cp1 = cb1 * 16 + lr;
      f32x4 acc2[2][2];
#pragma unroll
      for (int mi = 0; mi < 2; ++mi) { acc2[mi][0] = ZERO4; acc2[mi][1] = ZERO4; }
#pragma unroll
      for (int kb = 0; kb < 6; ++kb) {
        const short8 bf0 = *reinterpret_cast<const short8*>(
            &wp_c[((cb0 * 6 + kb) * 64 + l) * 8]);
        const short8 bf1 = *reinterpret_cast<const short8*>(
            &wp_c[((cb1 * 6 + kb) * 64 + l) * 8]);
#pragma unroll
        for (int mi = 0; mi < 2; ++mi) {
          const int mt = hf * 2 + mi;
          const short8 af = *reinterpret_cast<const short8*>(
              &o_lds[(mt * 16 + lr) * 200 + kb * 32 + lq * 8]);
          acc2[mi][0] = MFMA16(af, bf0, acc2[mi][0]);
          acc2[mi][1] = MFMA16(af, bf1, acc2[mi][1]);
        }
      }
      const float bb0 = b_proj[cp0], bb1 = b_proj[cp1];
#pragma unroll
      for (int mi = 0; mi < 2; ++mi) {
        const int mt = hf * 2 + mi;
        const int n0 = mt * 16 + lq * 4;
#pragma unroll
        for (int r = 0; r < 4; ++r) {
          const int n = n0 + r;
          if (n < 49) {                    // both 64B chunks of the 128B line together
            op[n * 192 + cp0] = acc2[mi][0][r] + bb0;
            op[n * 192 + cp1] = acc2[mi][1][r] + bb1;
          }
        }
      }
    }
  }
}

extern "C" void kernel_launch(void* const* d_in, const int* in_sizes, int n_in,
                              void* d_out, int out_size, void* d_ws, size_t ws_size,
                              hipStream_t stream) {
  const float* x     = (const float*)d_in[0];
  const float* qg    = (const float*)d_in[1];
  const float* wqkv  = (const float*)d_in[2];
  const float* bqkv  = (const float*)d_in[3];
  const float* btab  = (const float*)d_in[4];
  const float* wproj = (const float*)d_in[5];
  const float* bproj = (const float*)d_in[6];
  float* out = (float*)d_out;

  char* ws = (char*)d_ws;
  unsigned short* wq_c  = (unsigned short*)(ws);            // 147456 B
  unsigned short* wp_c  = (unsigned short*)(ws + 147456);   //  73728 B (uses 36864)
  unsigned short* q_bf  = (unsigned short*)(ws + 221184);   // 786432 B
  float* bias_c         = (float*)(ws + 1007616);           //  98304 B

  hipLaunchKernelGGL(prep_kernel, dim3(1536), dim3(256), 0, stream,
                     qg, wqkv, wproj, btab, wq_c, wp_c, q_bf, bias_c);
  hipLaunchKernelGGL(fused_win_attn, dim3(2048), dim3(512), 79360, stream,
                     x, bqkv, bproj, wq_c, wp_c, q_bf, bias_c, out);
}

// Round 22
// 75.372 us; speedup vs baseline: 1.0261x; 1.0261x over previous
//
#include <hip/hip_runtime.h>
#include <hip/hip_bf16.h>

typedef __attribute__((ext_vector_type(8))) short short8;   // 8 bf16 = MFMA A/B frag
typedef __attribute__((ext_vector_type(4))) short short4v;  // 4 bf16
typedef __attribute__((ext_vector_type(4))) float f32x4;    // MFMA C/D
typedef __attribute__((ext_vector_type(4))) unsigned int uint32x4;

#define MFMA16(A,B,C) __builtin_amdgcn_mfma_f32_16x16x32_bf16((A),(B),(C),0,0,0)

static __device__ __forceinline__ unsigned short f2bf(float f) {
  return __builtin_bit_cast(unsigned short, __float2bfloat16(f));  // single v_cvt, RTNE
}

// ---------------- prep: tables in MFMA-fragment order (identical to R11) ----------------
__global__ void prep_kernel(const float* __restrict__ qg,
                            const float* __restrict__ wqkv,
                            const float* __restrict__ wproj,
                            const float* __restrict__ btab,
                            unsigned short* __restrict__ wq_c,
                            unsigned short* __restrict__ wp_c,
                            unsigned short* __restrict__ q_bf,
                            float* __restrict__ bias_c)
{
  const int t = blockIdx.x * 256 + threadIdx.x;
  if (t < 32*6*64*32) {
    const int d = t & 31, n = (t >> 5) & 63;
    const int bh = t >> 11;
    const int h = bh % 6, b = bh / 6;
    float v = 0.f;
    if (n < 49) v = qg[((b * 6 + h) * 49 + n) * 32 + d] * 0.17677669529663687f;
    q_bf[t] = f2bf(v);
  }
  if (t < 8*3*6*64*8) {
    const int e = t & 7, l = (t >> 3) & 63;
    const int kb = (t >> 9) % 6, g = (t >> 9) / 6;
    const int ct = g % 3, wv = g / 3;
    const int j = wv * 48 + ct * 16 + (l & 15);
    const int c = kb * 32 + (l >> 4) * 8 + e;
    wq_c[t] = f2bf(wqkv[j * 192 + c]);
  }
  if (t < 2*6*6*64*8) {
    const int e = t & 7, l = (t >> 3) & 63;
    const int kb = (t >> 9) % 6, g = (t >> 9) / 6;
    const int ct = g % 6, cc = g / 6;
    const int cp = cc * 96 + ct * 16 + (l & 15);
    const int c = kb * 32 + (l >> 4) * 8 + e;
    wp_c[t] = f2bf(wproj[cp * 192 + c]);
  }
  if (t < 6*4*64*16) {
    const int i4 = t & 15;
    const int mt = i4 >> 2, r = i4 & 3;
    const int l = (t >> 4) & 63;
    const int nt = (t >> 10) & 3;
    const int h = t >> 12;
    // PERMUTED m so that P values land in PV A-frag order in-lane (no shuffle)
    const int m = (l >> 4) * 8 + (mt & 1) * 4 + r + (mt >> 1) * 32;
    const int n = nt * 16 + (l & 15);
    float v;
    if (m >= 49) v = -1e30f;            // mask padded keys (exp -> 0)
    else if (n >= 49) v = 0.f;          // padded query rows: any finite value
    else {
      const int ci = n / 7, cj = n % 7, mi = m / 7, mj = m % 7;
      const int idx = (ci - mi + 6) * 13 + (cj - mj + 6);
      v = btab[idx * 6 + h];
    }
    bias_c[t] = v;
  }
}

// ---------------- fused window attention (R20 champion restored) ----------------
// LDS: x_lds[64][200] @0 | k_lds[6][64][36] @12800 | vT_lds[6][32][68] @26624
//   o_lds[64][200] @0 (aliases dead x). total 79360 B -> 2 blocks/CU. 3 barriers.
// Stage 4 (line-owner, R20): an out row = six 128B L2 lines; each line = two 64B
// 16-col chunks. Wave wv<6 owns the 32-col pair (full lines) cols wv*32..+31;
// acc2[4][2], A-read shared by both halves, both chunks of a line stored
// back-to-back -> no half-dirty evictions. B loaded once per pair (4x less wp_c
// L2 traffic than R16). b_proj hoisted above the MFMA loop (store-chain dep).
// Session history: R21's register-lean split (12 items, 2x B loads) was WORSE
// (92 vs 89.4 us) and only cut junk 4MB -> residual ~15MB W junk is inherent.
// __launch_bounds__(512,4): 64-VGPR envelope.
__global__ __launch_bounds__(512, 4)
void fused_win_attn(const float* __restrict__ x,
                    const float* __restrict__ b_qkv,
                    const float* __restrict__ b_proj,
                    const unsigned short* __restrict__ wq_c,
                    const unsigned short* __restrict__ wp_c,
                    const unsigned short* __restrict__ q_bf,
                    const float* __restrict__ bias_c,
                    float* __restrict__ out)
{
  extern __shared__ unsigned short lds[];
  unsigned short* x_lds  = lds;
  unsigned short* k_lds  = lds + 12800;
  unsigned short* vT_lds = lds + 26624;
  unsigned short* o_lds  = lds;           // aliases dead x region during stage 3+

  const f32x4 ZERO4 = {0.f, 0.f, 0.f, 0.f};
  const int tid = threadIdx.x;
  const int wv = tid >> 6;
  const int l  = tid & 63;
  const int lr = l & 15;
  const int lq = l >> 4;
  const int w  = blockIdx.x;

  // ---- stage 1: x -> LDS bf16, zero-pad rows 49..63
  {
    const float* xw = x + (size_t)w * (49 * 192);
    for (int i = tid; i < 2352; i += 512) {
      const float4 v = *reinterpret_cast<const float4*>(xw + i * 4);
      const int e = i * 4;
      const int row = e / 192, col = e % 192;
      short4v pk;
      pk[0] = (short)f2bf(v.x); pk[1] = (short)f2bf(v.y);
      pk[2] = (short)f2bf(v.z); pk[3] = (short)f2bf(v.w);
      *reinterpret_cast<short4v*>(&x_lds[row * 200 + col]) = pk;
    }
    for (int i = tid; i < 720; i += 512) {
      const int e = i * 4;
      const int row = 49 + e / 192, col = e % 192;
      short4v z = {0, 0, 0, 0};
      *reinterpret_cast<short4v*>(&x_lds[row * 200 + col]) = z;
    }
  }
  __syncthreads();

  // ---- stage 2: kv = x @ w_qkv^T + b_qkv  -> k_lds, vT_lds (bf16)
  {
    short8 afr[4][6];
#pragma unroll
    for (int mt = 0; mt < 4; ++mt)
#pragma unroll
      for (int kb = 0; kb < 6; ++kb)
        afr[mt][kb] = *reinterpret_cast<const short8*>(
            &x_lds[(mt * 16 + lr) * 200 + kb * 32 + lq * 8]);

    for (int ct = 0; ct < 3; ++ct) {
      const int j = wv * 48 + ct * 16 + lr;   // 0..383
      short8 bfr[6];
#pragma unroll
      for (int kb = 0; kb < 6; ++kb)
        bfr[kb] = *reinterpret_cast<const short8*>(
            &wq_c[((((wv * 3) + ct) * 6 + kb) * 64 + l) * 8]);
      const float bq = b_qkv[j];
      f32x4 acc[4];
#pragma unroll
      for (int mt = 0; mt < 4; ++mt) acc[mt] = ZERO4;
#pragma unroll
      for (int kb = 0; kb < 6; ++kb)
#pragma unroll
        for (int mt = 0; mt < 4; ++mt)
          acc[mt] = MFMA16(afr[mt][kb], bfr[kb], acc[mt]);

      if (j < 192) {                  // K: k_lds[h][n][36-pad]
        const int h = j >> 5, d = j & 31;
#pragma unroll
        for (int mt = 0; mt < 4; ++mt) {
          const int n0 = mt * 16 + lq * 4;
#pragma unroll
          for (int r = 0; r < 4; ++r)
            k_lds[h * 2304 + (n0 + r) * 36 + d] = f2bf(acc[mt][r] + bq);
        }
      } else {                        // V: vT_lds[h][d][68-pad]
        const int jj = j - 192, h = jj >> 5, d = jj & 31;
#pragma unroll
        for (int mt = 0; mt < 4; ++mt) {
          const int n0 = mt * 16 + lq * 4;
          short4v pk;
#pragma unroll
          for (int r = 0; r < 4; ++r) pk[r] = (short)f2bf(acc[mt][r] + bq);
          *reinterpret_cast<short4v*>(&vT_lds[h * 2176 + d * 68 + n0]) = pk;
        }
      }
    }
  }
  __syncthreads();   // x dead; o_lds (@0) writable in stage 3

  // ---- stage 3: attention, permuted swapped QK^T; normalized O written directly
  const int nt = wv & 3;
  const int img = w >> 6;
  const int rowbase = (lr >> 2) * 8 + (lr & 3);   // permuted K-row base per lane
#pragma unroll
  for (int rd = 0; rd < 3; ++rd) {
    const int h = (wv >> 2) + 2 * rd;
    const short8 aq = *reinterpret_cast<const short8*>(
        &q_bf[((img * 6 + h) * 64 + nt * 16 + lr) * 32 + lq * 8]);
    f32x4 s[4];
#pragma unroll
    for (int mt = 0; mt < 4; ++mt) {
      const int row = rowbase + (mt & 1) * 4 + (mt >> 1) * 32;   // f(mt, lr)
      const unsigned short* kp = &k_lds[h * 2304 + row * 36 + lq * 8];
      const short4v k0 = *reinterpret_cast<const short4v*>(kp);
      const short4v k1 = *reinterpret_cast<const short4v*>(kp + 4);
      short8 bk;
      bk[0]=k0[0]; bk[1]=k0[1]; bk[2]=k0[2]; bk[3]=k0[3];
      bk[4]=k1[0]; bk[5]=k1[1]; bk[6]=k1[2]; bk[7]=k1[3];
      s[mt] = MFMA16(bk, aq, ZERO4);          // D = S^T (permuted m order)
    }
    // bias + exp; pack P (unnormalized) into PV A-frag order IN-LANE
    const float* bc = bias_c + ((h * 4 + nt) * 64 + l) * 16;
    float lsum = 0.f;
    unsigned int pa_u[4][2];
#pragma unroll
    for (int mt = 0; mt < 4; ++mt) {
      const float4 b4 = *reinterpret_cast<const float4*>(bc + mt * 4);
      const float p0 = __expf(s[mt][0] + b4.x);
      const float p1 = __expf(s[mt][1] + b4.y);
      const float p2 = __expf(s[mt][2] + b4.z);
      const float p3 = __expf(s[mt][3] + b4.w);
      lsum += (p0 + p1) + (p2 + p3);
      pa_u[mt][0] = (unsigned int)f2bf(p0) | ((unsigned int)f2bf(p1) << 16);
      pa_u[mt][1] = (unsigned int)f2bf(p2) | ((unsigned int)f2bf(p3) << 16);
    }
    lsum += __shfl_xor(lsum, 16, 64);
    lsum += __shfl_xor(lsum, 32, 64);
    const float rs = 1.0f / lsum;
    float rinv[4];
#pragma unroll
    for (int r = 0; r < 4; ++r)
      rinv[r] = __shfl(rs, lq * 4 + r, 16);
    // PV: pa[kb] = {p[2kb][0..3], p[2kb+1][0..3]} — no LDS, no shuffle
    f32x4 o0 = ZERO4, o1 = ZERO4;
#pragma unroll
    for (int kb = 0; kb < 2; ++kb) {
      uint32x4 uu;
      uu[0] = pa_u[2*kb][0]; uu[1] = pa_u[2*kb][1];
      uu[2] = pa_u[2*kb+1][0]; uu[3] = pa_u[2*kb+1][1];
      const short8 pa = __builtin_bit_cast(short8, uu);
      const unsigned short* vp0 = &vT_lds[h * 2176 + lr * 68 + kb * 32 + lq * 8];
      const unsigned short* vp1 = &vT_lds[h * 2176 + (16 + lr) * 68 + kb * 32 + lq * 8];
      const short4v a0 = *reinterpret_cast<const short4v*>(vp0);
      const short4v a1 = *reinterpret_cast<const short4v*>(vp0 + 4);
      short8 bv0; bv0[0]=a0[0];bv0[1]=a0[1];bv0[2]=a0[2];bv0[3]=a0[3];
                  bv0[4]=a1[0];bv0[5]=a1[1];bv0[6]=a1[2];bv0[7]=a1[3];
      o0 = MFMA16(pa, bv0, o0);
      const short4v c0 = *reinterpret_cast<const short4v*>(vp1);
      const short4v c1 = *reinterpret_cast<const short4v*>(vp1 + 4);
      short8 bv1; bv1[0]=c0[0];bv1[1]=c0[1];bv1[2]=c0[2];bv1[3]=c0[3];
                  bv1[4]=c1[0];bv1[5]=c1[1];bv1[6]=c1[2];bv1[7]=c1[3];
      o1 = MFMA16(pa, bv1, o1);
    }
    // normalized O -> o_lds (x region, dead) immediately
#pragma unroll
    for (int r = 0; r < 4; ++r) {
      const int n = nt * 16 + lq * 4 + r;
      o_lds[n * 200 + h * 32 + lr]      = f2bf(o0[r] * rinv[r]);
      o_lds[n * 200 + h * 32 + 16 + lr] = f2bf(o1[r] * rinv[r]);
    }
  }
  __syncthreads();   // O complete

  // ---- stage 4 (R20): line-owner pair-tiles; waves 0..5 own cols wv*32..wv*32+31
  if (wv < 6) {
    float* op = out + (size_t)w * 9408;
    const int cb0 = wv * 2, cb1 = wv * 2 + 1;      // 16-col block indices
    const int cp0 = cb0 * 16 + lr, cp1 = cb1 * 16 + lr;
    const float bb0 = b_proj[cp0], bb1 = b_proj[cp1];   // hoisted: no store-chain dep
    f32x4 acc2[4][2];
#pragma unroll
    for (int mt = 0; mt < 4; ++mt) { acc2[mt][0] = ZERO4; acc2[mt][1] = ZERO4; }
#pragma unroll
    for (int kb = 0; kb < 6; ++kb) {
      const short8 bf0 = *reinterpret_cast<const short8*>(
          &wp_c[((cb0 * 6 + kb) * 64 + l) * 8]);
      const short8 bf1 = *reinterpret_cast<const short8*>(
          &wp_c[((cb1 * 6 + kb) * 64 + l) * 8]);
#pragma unroll
      for (int mt = 0; mt < 4; ++mt) {
        const short8 af = *reinterpret_cast<const short8*>(
            &o_lds[(mt * 16 + lr) * 200 + kb * 32 + lq * 8]);
        acc2[mt][0] = MFMA16(af, bf0, acc2[mt][0]);
        acc2[mt][1] = MFMA16(af, bf1, acc2[mt][1]);
      }
    }
#pragma unroll
    for (int mt = 0; mt < 4; ++mt) {
      const int n0 = mt * 16 + lq * 4;
#pragma unroll
      for (int r = 0; r < 4; ++r) {
        const int n = n0 + r;
        if (n < 49) {                       // both 64B chunks of the 128B line together
          op[n * 192 + cp0] = acc2[mt][0][r] + bb0;
          op[n * 192 + cp1] = acc2[mt][1][r] + bb1;
        }
      }
    }
  }
}

extern "C" void kernel_launch(void* const* d_in, const int* in_sizes, int n_in,
                              void* d_out, int out_size, void* d_ws, size_t ws_size,
                              hipStream_t stream) {
  const float* x     = (const float*)d_in[0];
  const float* qg    = (const float*)d_in[1];
  const float* wqkv  = (const float*)d_in[2];
  const float* bqkv  = (const float*)d_in[3];
  const float* btab  = (const float*)d_in[4];
  const float* wproj = (const float*)d_in[5];
  const float* bproj = (const float*)d_in[6];
  float* out = (float*)d_out;

  char* ws = (char*)d_ws;
  unsigned short* wq_c  = (unsigned short*)(ws);            // 147456 B
  unsigned short* wp_c  = (unsigned short*)(ws + 147456);   //  73728 B (uses 36864)
  unsigned short* q_bf  = (unsigned short*)(ws + 221184);   // 786432 B
  float* bias_c         = (float*)(ws + 1007616);           //  98304 B

  hipLaunchKernelGGL(prep_kernel, dim3(1536), dim3(256), 0, stream,
                     qg, wqkv, wproj, btab, wq_c, wp_c, q_bf, bias_c);
  hipLaunchKernelGGL(fused_win_attn, dim3(2048), dim3(512), 79360, stream,
                     x, bqkv, bproj, wq_c, wp_c, q_bf, bias_c, out);
}

// Round 23
// 74.139 us; speedup vs baseline: 1.0432x; 1.0166x over previous
//
#include <hip/hip_runtime.h>
#include <hip/hip_bf16.h>

typedef __attribute__((ext_vector_type(8))) short short8;   // 8 bf16 = MFMA A/B frag
typedef __attribute__((ext_vector_type(4))) short short4v;  // 4 bf16
typedef __attribute__((ext_vector_type(4))) float f32x4;    // MFMA C/D
typedef __attribute__((ext_vector_type(4))) unsigned int uint32x4;

#define MFMA16(A,B,C) __builtin_amdgcn_mfma_f32_16x16x32_bf16((A),(B),(C),0,0,0)

static __device__ __forceinline__ unsigned short f2bf(float f) {
  return __builtin_bit_cast(unsigned short, __float2bfloat16(f));  // single v_cvt, RTNE
}

// ---------------- prep: tables in MFMA-fragment order (identical to R11) ----------------
__global__ void prep_kernel(const float* __restrict__ qg,
                            const float* __restrict__ wqkv,
                            const float* __restrict__ wproj,
                            const float* __restrict__ btab,
                            unsigned short* __restrict__ wq_c,
                            unsigned short* __restrict__ wp_c,
                            unsigned short* __restrict__ q_bf,
                            float* __restrict__ bias_c)
{
  const int t = blockIdx.x * 256 + threadIdx.x;
  if (t < 32*6*64*32) {
    const int d = t & 31, n = (t >> 5) & 63;
    const int bh = t >> 11;
    const int h = bh % 6, b = bh / 6;
    float v = 0.f;
    if (n < 49) v = qg[((b * 6 + h) * 49 + n) * 32 + d] * 0.17677669529663687f;
    q_bf[t] = f2bf(v);
  }
  if (t < 8*3*6*64*8) {
    const int e = t & 7, l = (t >> 3) & 63;
    const int kb = (t >> 9) % 6, g = (t >> 9) / 6;
    const int ct = g % 3, wv = g / 3;
    const int j = wv * 48 + ct * 16 + (l & 15);
    const int c = kb * 32 + (l >> 4) * 8 + e;
    wq_c[t] = f2bf(wqkv[j * 192 + c]);
  }
  if (t < 2*6*6*64*8) {
    const int e = t & 7, l = (t >> 3) & 63;
    const int kb = (t >> 9) % 6, g = (t >> 9) / 6;
    const int ct = g % 6, cc = g / 6;
    const int cp = cc * 96 + ct * 16 + (l & 15);
    const int c = kb * 32 + (l >> 4) * 8 + e;
    wp_c[t] = f2bf(wproj[cp * 192 + c]);
  }
  if (t < 6*4*64*16) {
    const int i4 = t & 15;
    const int mt = i4 >> 2, r = i4 & 3;
    const int l = (t >> 4) & 63;
    const int nt = (t >> 10) & 3;
    const int h = t >> 12;
    // PERMUTED m so that P values land in PV A-frag order in-lane (no shuffle)
    const int m = (l >> 4) * 8 + (mt & 1) * 4 + r + (mt >> 1) * 32;
    const int n = nt * 16 + (l & 15);
    float v;
    if (m >= 49) v = -1e30f;            // mask padded keys (exp -> 0)
    else if (n >= 49) v = 0.f;          // padded query rows: any finite value
    else {
      const int ci = n / 7, cj = n % 7, mi = m / 7, mj = m % 7;
      const int idx = (ci - mi + 6) * 13 + (cj - mj + 6);
      v = btab[idx * 6 + h];
    }
    bias_c[t] = v;
  }
}

// ---------------- fused window attention (R20/R22 champion + hoisted aq loads) ----------------
// LDS: x_lds[64][200] @0 | k_lds[6][64][36] @12800 | vT_lds[6][32][68] @26624
//   o_lds[64][200] @0 (aliases dead x). total 79360 B -> 2 blocks/CU. 3 barriers.
// Stage 3: all 3 aq fragments (h = ch+2rd) hoisted above the rd loop (T14
// issue-early) so their global-load latencies overlap each other + the rd=0
// K-reads, instead of heading each rd's dependency chain. +8 VGPR transient.
// Stage 4 (line-owner, R20): wave wv<6 owns 32-col pair (full 128B lines);
// both 64B chunks of each line stored back-to-back -> no half-dirty evictions;
// B loaded once per pair. WRITE_SIZE ~95.6MB is this structure's floor
// (R21 ablation: residual ~15MB W junk is inherent, not spill/line-split).
// __launch_bounds__(512,4): 64-VGPR envelope; tripwire = WRITE_SIZE >100MB.
__global__ __launch_bounds__(512, 4)
void fused_win_attn(const float* __restrict__ x,
                    const float* __restrict__ b_qkv,
                    const float* __restrict__ b_proj,
                    const unsigned short* __restrict__ wq_c,
                    const unsigned short* __restrict__ wp_c,
                    const unsigned short* __restrict__ q_bf,
                    const float* __restrict__ bias_c,
                    float* __restrict__ out)
{
  extern __shared__ unsigned short lds[];
  unsigned short* x_lds  = lds;
  unsigned short* k_lds  = lds + 12800;
  unsigned short* vT_lds = lds + 26624;
  unsigned short* o_lds  = lds;           // aliases dead x region during stage 3+

  const f32x4 ZERO4 = {0.f, 0.f, 0.f, 0.f};
  const int tid = threadIdx.x;
  const int wv = tid >> 6;
  const int l  = tid & 63;
  const int lr = l & 15;
  const int lq = l >> 4;
  const int w  = blockIdx.x;

  // ---- stage 1: x -> LDS bf16, zero-pad rows 49..63
  {
    const float* xw = x + (size_t)w * (49 * 192);
    for (int i = tid; i < 2352; i += 512) {
      const float4 v = *reinterpret_cast<const float4*>(xw + i * 4);
      const int e = i * 4;
      const int row = e / 192, col = e % 192;
      short4v pk;
      pk[0] = (short)f2bf(v.x); pk[1] = (short)f2bf(v.y);
      pk[2] = (short)f2bf(v.z); pk[3] = (short)f2bf(v.w);
      *reinterpret_cast<short4v*>(&x_lds[row * 200 + col]) = pk;
    }
    for (int i = tid; i < 720; i += 512) {
      const int e = i * 4;
      const int row = 49 + e / 192, col = e % 192;
      short4v z = {0, 0, 0, 0};
      *reinterpret_cast<short4v*>(&x_lds[row * 200 + col]) = z;
    }
  }
  __syncthreads();

  // ---- stage 2: kv = x @ w_qkv^T + b_qkv  -> k_lds, vT_lds (bf16)
  {
    short8 afr[4][6];
#pragma unroll
    for (int mt = 0; mt < 4; ++mt)
#pragma unroll
      for (int kb = 0; kb < 6; ++kb)
        afr[mt][kb] = *reinterpret_cast<const short8*>(
            &x_lds[(mt * 16 + lr) * 200 + kb * 32 + lq * 8]);

    for (int ct = 0; ct < 3; ++ct) {
      const int j = wv * 48 + ct * 16 + lr;   // 0..383
      short8 bfr[6];
#pragma unroll
      for (int kb = 0; kb < 6; ++kb)
        bfr[kb] = *reinterpret_cast<const short8*>(
            &wq_c[((((wv * 3) + ct) * 6 + kb) * 64 + l) * 8]);
      const float bq = b_qkv[j];
      f32x4 acc[4];
#pragma unroll
      for (int mt = 0; mt < 4; ++mt) acc[mt] = ZERO4;
#pragma unroll
      for (int kb = 0; kb < 6; ++kb)
#pragma unroll
        for (int mt = 0; mt < 4; ++mt)
          acc[mt] = MFMA16(afr[mt][kb], bfr[kb], acc[mt]);

      if (j < 192) {                  // K: k_lds[h][n][36-pad]
        const int h = j >> 5, d = j & 31;
#pragma unroll
        for (int mt = 0; mt < 4; ++mt) {
          const int n0 = mt * 16 + lq * 4;
#pragma unroll
          for (int r = 0; r < 4; ++r)
            k_lds[h * 2304 + (n0 + r) * 36 + d] = f2bf(acc[mt][r] + bq);
        }
      } else {                        // V: vT_lds[h][d][68-pad]
        const int jj = j - 192, h = jj >> 5, d = jj & 31;
#pragma unroll
        for (int mt = 0; mt < 4; ++mt) {
          const int n0 = mt * 16 + lq * 4;
          short4v pk;
#pragma unroll
          for (int r = 0; r < 4; ++r) pk[r] = (short)f2bf(acc[mt][r] + bq);
          *reinterpret_cast<short4v*>(&vT_lds[h * 2176 + d * 68 + n0]) = pk;
        }
      }
    }
  }
  __syncthreads();   // x dead; o_lds (@0) writable in stage 3

  // ---- stage 3: attention, permuted swapped QK^T; aq loads hoisted (issue-early)
  const int nt = wv & 3;
  const int img = w >> 6;
  const int rowbase = (lr >> 2) * 8 + (lr & 3);   // permuted K-row base per lane
  short8 aq_all[3];
#pragma unroll
  for (int rd = 0; rd < 3; ++rd) {
    const int h = (wv >> 2) + 2 * rd;
    aq_all[rd] = *reinterpret_cast<const short8*>(
        &q_bf[((img * 6 + h) * 64 + nt * 16 + lr) * 32 + lq * 8]);
  }
#pragma unroll
  for (int rd = 0; rd < 3; ++rd) {
    const int h = (wv >> 2) + 2 * rd;
    const short8 aq = aq_all[rd];
    f32x4 s[4];
#pragma unroll
    for (int mt = 0; mt < 4; ++mt) {
      const int row = rowbase + (mt & 1) * 4 + (mt >> 1) * 32;   // f(mt, lr)
      const unsigned short* kp = &k_lds[h * 2304 + row * 36 + lq * 8];
      const short4v k0 = *reinterpret_cast<const short4v*>(kp);
      const short4v k1 = *reinterpret_cast<const short4v*>(kp + 4);
      short8 bk;
      bk[0]=k0[0]; bk[1]=k0[1]; bk[2]=k0[2]; bk[3]=k0[3];
      bk[4]=k1[0]; bk[5]=k1[1]; bk[6]=k1[2]; bk[7]=k1[3];
      s[mt] = MFMA16(bk, aq, ZERO4);          // D = S^T (permuted m order)
    }
    // bias + exp; pack P (unnormalized) into PV A-frag order IN-LANE
    const float* bc = bias_c + ((h * 4 + nt) * 64 + l) * 16;
    float lsum = 0.f;
    unsigned int pa_u[4][2];
#pragma unroll
    for (int mt = 0; mt < 4; ++mt) {
      const float4 b4 = *reinterpret_cast<const float4*>(bc + mt * 4);
      const float p0 = __expf(s[mt][0] + b4.x);
      const float p1 = __expf(s[mt][1] + b4.y);
      const float p2 = __expf(s[mt][2] + b4.z);
      const float p3 = __expf(s[mt][3] + b4.w);
      lsum += (p0 + p1) + (p2 + p3);
      pa_u[mt][0] = (unsigned int)f2bf(p0) | ((unsigned int)f2bf(p1) << 16);
      pa_u[mt][1] = (unsigned int)f2bf(p2) | ((unsigned int)f2bf(p3) << 16);
    }
    lsum += __shfl_xor(lsum, 16, 64);
    lsum += __shfl_xor(lsum, 32, 64);
    const float rs = 1.0f / lsum;
    float rinv[4];
#pragma unroll
    for (int r = 0; r < 4; ++r)
      rinv[r] = __shfl(rs, lq * 4 + r, 16);
    // PV: pa[kb] = {p[2kb][0..3], p[2kb+1][0..3]} — no LDS, no shuffle
    f32x4 o0 = ZERO4, o1 = ZERO4;
#pragma unroll
    for (int kb = 0; kb < 2; ++kb) {
      uint32x4 uu;
      uu[0] = pa_u[2*kb][0]; uu[1] = pa_u[2*kb][1];
      uu[2] = pa_u[2*kb+1][0]; uu[3] = pa_u[2*kb+1][1];
      const short8 pa = __builtin_bit_cast(short8, uu);
      const unsigned short* vp0 = &vT_lds[h * 2176 + lr * 68 + kb * 32 + lq * 8];
      const unsigned short* vp1 = &vT_lds[h * 2176 + (16 + lr) * 68 + kb * 32 + lq * 8];
      const short4v a0 = *reinterpret_cast<const short4v*>(vp0);
      const short4v a1 = *reinterpret_cast<const short4v*>(vp0 + 4);
      short8 bv0; bv0[0]=a0[0];bv0[1]=a0[1];bv0[2]=a0[2];bv0[3]=a0[3];
                  bv0[4]=a1[0];bv0[5]=a1[1];bv0[6]=a1[2];bv0[7]=a1[3];
      o0 = MFMA16(pa, bv0, o0);
      const short4v c0 = *reinterpret_cast<const short4v*>(vp1);
      const short4v c1 = *reinterpret_cast<const short4v*>(vp1 + 4);
      short8 bv1; bv1[0]=c0[0];bv1[1]=c0[1];bv1[2]=c0[2];bv1[3]=c0[3];
                  bv1[4]=c1[0];bv1[5]=c1[1];bv1[6]=c1[2];bv1[7]=c1[3];
      o1 = MFMA16(pa, bv1, o1);
    }
    // normalized O -> o_lds (x region, dead) immediately
#pragma unroll
    for (int r = 0; r < 4; ++r) {
      const int n = nt * 16 + lq * 4 + r;
      o_lds[n * 200 + h * 32 + lr]      = f2bf(o0[r] * rinv[r]);
      o_lds[n * 200 + h * 32 + 16 + lr] = f2bf(o1[r] * rinv[r]);
    }
  }
  __syncthreads();   // O complete

  // ---- stage 4 (R20): line-owner pair-tiles; waves 0..5 own cols wv*32..wv*32+31
  if (wv < 6) {
    float* op = out + (size_t)w * 9408;
    const int cb0 = wv * 2, cb1 = wv * 2 + 1;      // 16-col block indices
    const int cp0 = cb0 * 16 + lr, cp1 = cb1 * 16 + lr;
    const float bb0 = b_proj[cp0], bb1 = b_proj[cp1];   // hoisted: no store-chain dep
    f32x4 acc2[4][2];
#pragma unroll
    for (int mt = 0; mt < 4; ++mt) { acc2[mt][0] = ZERO4; acc2[mt][1] = ZERO4; }
#pragma unroll
    for (int kb = 0; kb < 6; ++kb) {
      const short8 bf0 = *reinterpret_cast<const short8*>(
          &wp_c[((cb0 * 6 + kb) * 64 + l) * 8]);
      const short8 bf1 = *reinterpret_cast<const short8*>(
          &wp_c[((cb1 * 6 + kb) * 64 + l) * 8]);
#pragma unroll
      for (int mt = 0; mt < 4; ++mt) {
        const short8 af = *reinterpret_cast<const short8*>(
            &o_lds[(mt * 16 + lr) * 200 + kb * 32 + lq * 8]);
        acc2[mt][0] = MFMA16(af, bf0, acc2[mt][0]);
        acc2[mt][1] = MFMA16(af, bf1, acc2[mt][1]);
      }
    }
#pragma unroll
    for (int mt = 0; mt < 4; ++mt) {
      const int n0 = mt * 16 + lq * 4;
#pragma unroll
      for (int r = 0; r < 4; ++r) {
        const int n = n0 + r;
        if (n < 49) {                       // both 64B chunks of the 128B line together
          op[n * 192 + cp0] = acc2[mt][0][r] + bb0;
          op[n * 192 + cp1] = acc2[mt][1][r] + bb1;
        }
      }
    }
  }
}

extern "C" void kernel_launch(void* const* d_in, const int* in_sizes, int n_in,
                              void* d_out, int out_size, void* d_ws, size_t ws_size,
                              hipStream_t stream) {
  const float* x     = (const float*)d_in[0];
  const float* qg    = (const float*)d_in[1];
  const float* wqkv  = (const float*)d_in[2];
  const float* bqkv  = (const float*)d_in[3];
  const float* btab  = (const float*)d_in[4];
  const float* wproj = (const float*)d_in[5];
  const float* bproj = (const float*)d_in[6];
  float* out = (float*)d_out;

  char* ws = (char*)d_ws;
  unsigned short* wq_c  = (unsigned short*)(ws);            // 147456 B
  unsigned short* wp_c  = (unsigned short*)(ws + 147456);   //  73728 B (uses 36864)
  unsigned short* q_bf  = (unsigned short*)(ws + 221184);   // 786432 B
  float* bias_c         = (float*)(ws + 1007616);           //  98304 B

  hipLaunchKernelGGL(prep_kernel, dim3(1536), dim3(256), 0, stream,
                     qg, wqkv, wproj, btab, wq_c, wp_c, q_bf, bias_c);
  hipLaunchKernelGGL(fused_win_attn, dim3(2048), dim3(512), 79360, stream,
                     x, bqkv, bproj, wq_c, wp_c, q_bf, bias_c, out);
}